// Round 6
// baseline (381.390 us; speedup 1.0000x reference)
//
#include <hip/hip_runtime.h>

#define NS    23      // columns per row (dose + 22 masks)
#define NSTR  22      // structures
#define NQ    6       // structure quads (4 x 8-bit counters per u32)
#define ND    85      // dose bins in the loss
#define NB    256     // histogram bins
#define H     0.4f    // bin width (covers [0, 102.4))
#define INV_H 2.5f
#define EPSF  1.1920929e-07f
#define BLK   256
#define MAXB  512                 // 2 blocks/CU x 256 CUs
#define TILE_B  (BLK * NS * 4)    // 23552 B per tile (256 rows x 92 B)
#define WSLICE  (64 * NS * 4)     // 5888 B: rows owned by one wave
#define BUF_B   23808             // last wave's 6x1KB chunk span
#define HW8     (2 * NB * NQ)     // 3072 u32 of packed 8-bit quad counters
#define GHIST_W (2 * NSTR * NB)   // 11264 u32 plain hist [2][22][256]
#define SLAB_OFF 65536            // byte offset of slab region in d_ws
#define RS_CH 16                  // slab-chunks in rsum kernel

// R6 theory: the INVARIANT across all 5 stuck-at-1.5TB/s kernels is the yp
// col-0 gather: 4B/row at 92B stride -> 2M distinct 64B lines = 128MB of
// hidden line-fill traffic (invisible in FETCH_SIZE: yp L3-resident) loading
// the XCD L2-fill/fabric path ~1TB/s on top of the 1.5TB/s HBM stream.
// Fix: pack_kernel streams yp coalesced and emits dose_p[N] (8MB); hist's
// per-row 4B DMA load becomes contiguous (4 lines/wave instead of 64).
typedef const __attribute__((address_space(1))) unsigned int* gp1_t;
typedef __attribute__((address_space(3)))       unsigned int* lp3_t;

__device__ __forceinline__ void gl_lds16(const void* g, void* l) {
    __builtin_amdgcn_global_load_lds((gp1_t)(uintptr_t)g, (lp3_t)(uintptr_t)l,
                                     16, 0, 0);
}
__device__ __forceinline__ void gl_lds4(const void* g, void* l) {
    __builtin_amdgcn_global_load_lds((gp1_t)(uintptr_t)g, (lp3_t)(uintptr_t)l,
                                     4, 0, 0);
}

// spread low 4 bits of v into the 4 byte lanes of a u32
__device__ __forceinline__ unsigned int quad_expand(unsigned int v) {
    return (v & 1u) | ((v & 2u) << 7) | ((v & 4u) << 14) | ((v & 8u) << 21);
}

// ---------------- Pass 0: pack yp col-0 into contiguous dose_p --------------
__global__ void dvh_pack_kernel(const float* __restrict__ yp,
                                float* __restrict__ dp,
                                size_t nf4, size_t totalF, int N)
{
    size_t g = (size_t)blockIdx.x * blockDim.x + threadIdx.x;
    const size_t stride = (size_t)gridDim.x * blockDim.x;
    const float4* yp4 = (const float4*)yp;
    for (; g < nf4; g += stride) {
        float4 v = yp4[g];
        unsigned int f0 = (unsigned int)((4 * g) % 23);   // col of .x
        unsigned int j  = (23u - f0) % 23u;               // j with col==0
        if (j < 4u) {
            float val = (j == 0) ? v.x : (j == 1) ? v.y : (j == 2) ? v.z : v.w;
            dp[(4 * g + j) / 23] = val;
        }
    }
    if (g == stride) {   // one thread handles the <4-float tail
        for (size_t f = 4 * nf4; f < totalF; ++f)
            if (f % 23 == 0) dp[f / 23] = yp[f];
    }
}

__global__ __launch_bounds__(BLK, 2) void dvh_hist_kernel(
    const float* __restrict__ yt,   // y_true f32, N x 23
    const float* __restrict__ yp,   // y_pred f32, N x 23 (remainder rows only)
    const float* __restrict__ dpsrc,// packed dose_p (stride 1) or yp (stride NS)
    int pstride,
    int N, int fullTiles,
    unsigned int* __restrict__ g_hist,   // [2][NSTR][NB] u32 plain
    unsigned int* __restrict__ g_slab)   // grid x HW8, or nullptr
{
    __shared__ unsigned int s_h8[2][NB][NQ];    // 12288 B packed 8-bit quads
    __shared__ char  s_tile[2][BUF_B];          // 2 x 23808 B
    __shared__ float s_p[2][BLK];               // 2 x 1024 B -> 61952 B total

    const int tid  = threadIdx.x;
    const int wid  = tid >> 6;
    const int lane = tid & 63;

    for (int i = tid; i < HW8; i += BLK) ((unsigned int*)s_h8)[i] = 0u;
    __syncthreads();

    auto stage = [&](int buf, size_t t) {
        const char* gsrc = (const char*)yt + t * (size_t)TILE_B + wid * WSLICE;
        char* lb = &s_tile[buf][wid * WSLICE];
#pragma unroll
        for (int k = 0; k < 6; ++k)
            gl_lds16(gsrc + k * 1024 + lane * 16, lb + k * 1024);
        gl_lds4(dpsrc + (t * BLK + wid * 64 + lane) * (size_t)pstride,
                &s_p[buf][wid * 64]);
    };

    auto scatter = [&](unsigned int bits, int qt, int qp) {
        unsigned int* ht = &s_h8[0][qt][0];
        unsigned int* hp = &s_h8[1][qp][0];
        unsigned int e0 = quad_expand(bits);
        unsigned int e1 = quad_expand(bits >> 4);
        unsigned int e2 = quad_expand(bits >> 8);
        unsigned int e3 = quad_expand(bits >> 12);
        unsigned int e4 = quad_expand(bits >> 16);
        unsigned int e5 = quad_expand(bits >> 20);
        if (e0) { atomicAdd(ht + 0, e0); atomicAdd(hp + 0, e0); }
        if (e1) { atomicAdd(ht + 1, e1); atomicAdd(hp + 1, e1); }
        if (e2) { atomicAdd(ht + 2, e2); atomicAdd(hp + 2, e2); }
        if (e3) { atomicAdd(ht + 3, e3); atomicAdd(hp + 3, e3); }
        if (e4) { atomicAdd(ht + 4, e4); atomicAdd(hp + 4, e4); }
        if (e5) { atomicAdd(ht + 5, e5); atomicAdd(hp + 5, e5); }
    };

    auto process = [&](int buf) {
        const unsigned int* row =
            (const unsigned int*)(&s_tile[buf][wid * WSLICE + lane * (NS * 4)]);
        float t0 = __uint_as_float(row[0]);
        unsigned int bits = 0;
#pragma unroll
        for (int s = 0; s < NSTR; ++s)
            bits |= (row[s + 1] != 0u ? 1u : 0u) << s;
        if (bits) {
            int qt = (int)(t0 * INV_H);
            qt = qt > 0 ? qt : 0;
            qt = qt < NB - 1 ? qt : NB - 1;
            float pr = fmaxf(s_p[buf][tid], 0.f);
            int qp = (int)(pr * INV_H);
            qp = qp < NB - 1 ? qp : NB - 1;
            scatter(bits, qt, qp);
        }
    };

    size_t t = blockIdx.x;
    const size_t S = gridDim.x;

    if (t < (size_t)fullTiles)     stage(0, t);
    if (t + S < (size_t)fullTiles) stage(1, t + S);

    int cur = 0;
    for (; t < (size_t)fullTiles; t += S) {
        if (t + S < (size_t)fullTiles) {
            asm volatile("s_waitcnt vmcnt(7)" ::: "memory");
        } else {
            asm volatile("s_waitcnt vmcnt(0)" ::: "memory");
        }
        __builtin_amdgcn_sched_barrier(0);

        process(cur);
        if (t + 2 * S < (size_t)fullTiles) stage(cur, t + 2 * S);
        cur ^= 1;
    }

    // ---- remainder rows: block 0, direct from global ----
    if (blockIdx.x == 0) {
        for (int n = fullTiles * BLK + tid; n < N; n += BLK) {
            const float* r = yt + (size_t)n * NS;
            float t0 = r[0];
            unsigned int bits = 0;
#pragma unroll
            for (int s = 0; s < NSTR; ++s)
                bits |= (__float_as_uint(r[s + 1]) != 0u ? 1u : 0u) << s;
            if (bits) {
                int qt = (int)(t0 * INV_H);
                qt = qt > 0 ? qt : 0;
                qt = qt < NB - 1 ? qt : NB - 1;
                float pr = fmaxf(yp[(size_t)n * NS], 0.f);
                int qp = (int)(pr * INV_H);
                qp = qp < NB - 1 ? qp : NB - 1;
                scatter(bits, qt, qp);
            }
        }
    }
    __syncthreads();

    if (g_slab) {
        unsigned int* slab = g_slab + (size_t)blockIdx.x * HW8;
        const unsigned int* h = (const unsigned int*)s_h8;
        for (int i = tid; i < HW8; i += BLK) slab[i] = h[i];
    } else {
        const unsigned int* h = (const unsigned int*)s_h8;
        for (int i = tid; i < HW8; i += BLK) {
            unsigned int w = h[i];
            if (!w) continue;
            int hs = i / (NB * NQ);
            int rem = i - hs * (NB * NQ);
            int q  = rem / NQ;
            int qd = rem - q * NQ;
#pragma unroll
            for (int j = 0; j < 4; ++j) {
                int s = 4 * qd + j;
                unsigned int c = (w >> (8 * j)) & 0xFFu;
                if (s < NSTR && c)
                    atomicAdd(&g_hist[(hs * NSTR + s) * NB + q], c);
            }
        }
    }
}

// ---------------- Pass 1b: reduce per-block quad slabs -> plain hist --------
__global__ void dvh_rsum_kernel(const unsigned int* __restrict__ g_slab,
                                int nslab,
                                unsigned int* __restrict__ g_hist)
{
    const int jblocks = HW8 / 256;               // 12
    int jb = blockIdx.x % jblocks;
    int cb = blockIdx.x / jblocks;
    int j  = jb * 256 + threadIdx.x;             // word index in [0, HW8)
    int chunk = (nslab + RS_CH - 1) / RS_CH;
    int b0 = cb * chunk;
    int b1 = b0 + chunk; if (b1 > nslab) b1 = nslab;

    unsigned int acc0 = 0, acc1 = 0, acc2 = 0, acc3 = 0;
    for (int b = b0; b < b1; ++b) {
        unsigned int w = g_slab[(size_t)b * HW8 + j];
        acc0 += w & 0xFFu;
        acc1 += (w >> 8) & 0xFFu;
        acc2 += (w >> 16) & 0xFFu;
        acc3 += (w >> 24) & 0xFFu;
    }

    int hs  = j / (NB * NQ);
    int rem = j - hs * (NB * NQ);
    int q   = rem / NQ;
    int qd  = rem - q * NQ;
    int sb  = 4 * qd;
    if (acc0)                  atomicAdd(&g_hist[(hs * NSTR + sb + 0) * NB + q], acc0);
    if (acc1 && sb + 1 < NSTR) atomicAdd(&g_hist[(hs * NSTR + sb + 1) * NB + q], acc1);
    if (acc2 && sb + 2 < NSTR) atomicAdd(&g_hist[(hs * NSTR + sb + 2) * NB + q], acc2);
    if (acc3 && sb + 3 < NSTR) atomicAdd(&g_hist[(hs * NSTR + sb + 3) * NB + q], acc3);
}

// ---------------- Pass 2: sigmoid-weighted reduce over plain hist -----------
__global__ void dvh_reduce_kernel(const unsigned int* __restrict__ g_hist,
                                  float* __restrict__ dsq)   // ND x NSTR
{
    int d = blockIdx.x;        // 0..84
    int lane = threadIdx.x;    // 0..63

    float at[NSTR], ap[NSTR], cn[NSTR];
#pragma unroll
    for (int s = 0; s < NSTR; ++s) { at[s] = 0.f; ap[s] = 0.f; cn[s] = 0.f; }

#pragma unroll
    for (int j = 0; j < NB / 64; ++j) {
        int q = lane + 64 * j;
        float c = ((float)q + 0.5f) * H;
        float wgt = 1.0f / (1.0f + __expf((float)d - c));   // sigmoid(c - d)
#pragma unroll
        for (int s = 0; s < NSTR; ++s) {
            float tv = (float)g_hist[s * NB + q];
            float pv = (float)g_hist[(NSTR + s) * NB + q];
            at[s] += wgt * tv;
            ap[s] += wgt * pv;
            cn[s] += tv;
        }
    }

#pragma unroll
    for (int s = 0; s < NSTR; ++s) {
#pragma unroll
        for (int o = 32; o; o >>= 1) {
            at[s] += __shfl_xor(at[s], o);
            ap[s] += __shfl_xor(ap[s], o);
            cn[s] += __shfl_xor(cn[s], o);
        }
    }

    if (lane == 0) {
#pragma unroll
        for (int s = 0; s < NSTR; ++s) {
            float diff = (at[s] - ap[s]) / (cn[s] + EPSF);
            dsq[d * NSTR + s] = diff * diff;
        }
    }
}

// ------- Pass 3: per-structure L2 over d, sum, scale (unchanged) ------------
__global__ void dvh_final_kernel(const float* __restrict__ dsq,
                                 float* __restrict__ out)
{
    int s = threadIdx.x;   // 0..63
    float r = 0.0f;
    if (s < NSTR) {
        float a = 0.0f;
        for (int d = 0; d < ND; ++d) a += dsq[d * NSTR + s];
        r = sqrtf(a);
    }
#pragma unroll
    for (int o = 32; o; o >>= 1) r += __shfl_xor(r, o);
    if (s == 0) out[0] = r / (float)(ND * NSTR);
}

extern "C" void kernel_launch(void* const* d_in, const int* in_sizes, int n_in,
                              void* d_out, int out_size, void* d_ws, size_t ws_size,
                              hipStream_t stream) {
    const float* yt = (const float*)d_in[0];
    const float* yp = (const float*)d_in[1];
    int N = in_sizes[0] / NS;
    size_t totalF = (size_t)N * NS;

    unsigned int* g_hist = (unsigned int*)d_ws;                 // 45056 B
    float* dsq = (float*)((char*)d_ws + GHIST_W * 4 + 128);     // 85*22*4 B

    int fullTiles = N / BLK;
    if (fullTiles > 0 && (N - fullTiles * BLK) * (NS * 4) < 1024) fullTiles -= 1;

    int grid = fullTiles < MAXB ? fullTiles : MAXB;
    if (grid < 1) grid = 1;

    size_t slabBytes = (size_t)grid * HW8 * 4;
    unsigned int* g_slab = nullptr;
    if (ws_size >= SLAB_OFF + slabBytes)
        g_slab = (unsigned int*)((char*)d_ws + SLAB_OFF);

    // packed dose_p region, after slabs (aligned to 256B)
    size_t dpOff = (SLAB_OFF + slabBytes + 255) & ~(size_t)255;
    float* dp = nullptr;
    if (ws_size >= dpOff + (size_t)N * 4)
        dp = (float*)((char*)d_ws + dpOff);

    hipMemsetAsync(d_ws, 0, GHIST_W * 4, stream);

    const float* dpsrc = dp ? (const float*)dp : yp;
    int pstride = dp ? 1 : NS;

    if (dp) {
        size_t nf4 = totalF / 4;
        int pgrid = 2048;
        dvh_pack_kernel<<<pgrid, 256, 0, stream>>>(yp, dp, nf4, totalF, N);
    }
    dvh_hist_kernel<<<grid, BLK, 0, stream>>>(yt, yp, dpsrc, pstride,
                                              N, fullTiles, g_hist, g_slab);
    if (g_slab)
        dvh_rsum_kernel<<<(HW8 / 256) * RS_CH, 256, 0, stream>>>(
            g_slab, grid, g_hist);
    dvh_reduce_kernel<<<ND, 64, 0, stream>>>(g_hist, dsq);
    dvh_final_kernel<<<1, 64, 0, stream>>>(dsq, (float*)d_out);
}